// Round 18
// baseline (64.900 us; speedup 1.0000x reference)
//
#include <hip/hip_runtime.h>

typedef __attribute__((ext_vector_type(8))) short bf16x8;
typedef __attribute__((ext_vector_type(4))) short bf16x4;
typedef __attribute__((ext_vector_type(4))) float f32x4;

#define MFMA16(A, Bv, C) __builtin_amdgcn_mfma_f32_16x16x32_bf16((A), (Bv), (C), 0, 0, 0)

static constexpr int NB = 4, NS = 4096, ND = 1024, NH = 64;

__device__ __forceinline__ unsigned short f2bf(float f) {
    union { float f; unsigned int u; } x; x.f = f;
    unsigned int r = x.u + 0x7fffu + ((x.u >> 16) & 1u);
    return (unsigned short)(r >> 16);
}

// async global->LDS, 16B per lane; LDS dest = wave-uniform base + lane*16
__device__ __forceinline__ void gload_lds16(const void* g, void* l) {
    __builtin_amdgcn_global_load_lds((const __attribute__((address_space(1))) void*)g,
                                     (__attribute__((address_space(3))) void*)l, 16, 0, 0);
}

// ---------------------------------------------------------------------------
// Kernel 0: W[D][H] fp32 -> wT[m*64+n][k] bf16  (192 x 1024, 384 KB, L2-hot)
// ---------------------------------------------------------------------------
__global__ __launch_bounds__(256) void wconv(
    const float* __restrict__ Wq, const float* __restrict__ Wk,
    const float* __restrict__ Wv, unsigned short* __restrict__ wT)
{
    int mn = blockIdx.x;                 // 0..191 = m*64 + n
    int m = mn >> 6, n = mn & 63;
    const float* W = (m == 0) ? Wq : (m == 1) ? Wk : Wv;
    unsigned short* dst = wT + (size_t)mn * ND;
    for (int k = threadIdx.x; k < ND; k += 256)
        dst[k] = f2bf(W[(size_t)k * NH + n]);
}

// ---------------------------------------------------------------------------
// Kernel 1: QKV projection — R9 config verbatim (local optimum: ~25 us).
// 512 blocks x 512 thr (8 waves), M-tile 32, N full 192, BK=64, 16 steps,
// 2 blocks/CU (16 waves/CU).
// ---------------------------------------------------------------------------
__global__ __launch_bounds__(512) void qkv_proj(
    const float* __restrict__ x, const unsigned short* __restrict__ wT,
    unsigned short* __restrict__ qo, unsigned short* __restrict__ ko,
    unsigned short* __restrict__ vt)
{
    __shared__ unsigned short Ws[2][192][64];   // [buf][n][k], XOR-swizzled chunks
    __shared__ unsigned short Xs[2][32][72];    // [buf][m][k], +8 pad
    __shared__ unsigned short Ls[32][72];       // v transpose staging

    const int tid  = threadIdx.x;               // 0..511
    const int lane = tid & 63;
    const int w    = tid >> 6;                  // 0..7
    const int lr   = lane & 15;
    const int lg   = lane >> 4;
    const int mg   = w >> 2;                    // M half (16 rows)
    const int cg   = w & 3;                     // N quarter (48 cols)
    const int mbase = blockIdx.x * 32;

    // W stage: instr = 8 rows x 128B; LDS[r][c] holds src[r][c ^ (r&7)]
    const int wr8 = lane >> 3;
    const int wck = (lane & 7) ^ wr8;
    // x: thread -> (row = tid&31, float4 slot = tid>>5)
    const int xrow = tid & 31;
    const int xcg  = tid >> 5;                  // 0..15

    f32x4 acc[3];
    #pragma unroll
    for (int f = 0; f < 3; ++f) acc[f] = (f32x4){0.f, 0.f, 0.f, 0.f};

    const float* xsrc = x + (size_t)(mbase + xrow) * ND + xcg * 4;

    #define STAGE_W(buf, kb)                                                         \
        do {                                                                         \
            _Pragma("unroll")                                                        \
            for (int i_ = 0; i_ < 3; ++i_) {                                         \
                int rb_ = w * 24 + i_ * 8;                                           \
                gload_lds16(wT + (size_t)(rb_ + wr8) * ND + (kb) + wck * 8,          \
                            &Ws[buf][rb_][0]);                                       \
            }                                                                        \
        } while (0)

    #define LOADX(kb) do { xr = *(const float4*)(xsrc + (kb)); } while (0)

    #define WRITEX(buf)                                                              \
        do {                                                                         \
            bf16x4 p_;                                                               \
            p_[0] = (short)f2bf(xr.x); p_[1] = (short)f2bf(xr.y);                    \
            p_[2] = (short)f2bf(xr.z); p_[3] = (short)f2bf(xr.w);                    \
            *(bf16x4*)&Xs[buf][xrow][xcg * 4] = p_;                                  \
        } while (0)

    float4 xr;
    STAGE_W(0, 0);
    LOADX(0);
    WRITEX(0);
    __syncthreads();

    for (int kt = 0; kt < 16; ++kt) {
        const int cur = kt & 1;
        if (kt + 1 < 16) {
            STAGE_W(cur ^ 1, (kt + 1) * 64);
            LOADX((kt + 1) * 64);
        }

        #pragma unroll
        for (int kk = 0; kk < 2; ++kk) {
            bf16x8 af = *(const bf16x8*)&Xs[cur][mg * 16 + lr][(kk * 4 + lg) * 8];
            #pragma unroll
            for (int f = 0; f < 3; ++f) {
                int row = cg * 48 + f * 16 + lr;
                bf16x8 bfr = *(const bf16x8*)&Ws[cur][row][((kk * 4 + lg) ^ (lr & 7)) * 8];
                acc[f] = MFMA16(af, bfr, acc[f]);
            }
        }

        if (kt + 1 < 16) WRITEX(cur ^ 1);   // Xs[next]: readers done a barrier ago
        __syncthreads();
    }

    // epilogue: frag (cg,f) -> n-block b16 = cg*3+f (16 cols, inside one of q/k/v)
    #pragma unroll
    for (int f = 0; f < 3; ++f) {
        int b16 = cg * 3 + f;
        int sel = b16 >> 2;
        int col = (b16 & 3) * 16 + lr;
        #pragma unroll
        for (int rr = 0; rr < 4; ++rr) {
            int mrow = mg * 16 + lg * 4 + rr;       // C/D: row=(lane>>4)*4+reg
            float v = acc[f][rr];
            if (sel == 0)
                qo[(size_t)(mbase + mrow) * NH + col] = f2bf(v * 0.125f);
            else if (sel == 1)
                ko[(size_t)(mbase + mrow) * NH + col] = f2bf(v);
            else
                Ls[mrow][col] = f2bf(v);
        }
    }
    __syncthreads();
    {   // transpose 32 s x 64 h: thread -> (h = tid>>3, 4-s strip)
        int h  = tid >> 3;                          // 0..63
        int s4 = (tid & 7) * 4;                     // 0..28
        bf16x4 v0;
        #pragma unroll
        for (int jj = 0; jj < 4; ++jj) v0[jj] = (short)Ls[s4 + jj][h];
        int b_ = mbase >> 12;
        int sb = (mbase & (NS - 1)) + s4;
        *(bf16x4*)(vt + ((size_t)(b_ * NH + h)) * NS + sb) = v0;
    }
    #undef STAGE_W
    #undef LOADX
    #undef WRITEX
}

// ---------------------------------------------------------------------------
// Kernel 2: attention phase A — QBLK=128, 8 waves/block (512 THREADS — R17's
// failure was launching this with 256). K/V staging amortized over 8 waves
// (2 gload_lds/wave/tile); LDS 50.4 KB -> 3 blocks/CU = 24 waves/CU.
// Swapped-operand softmax (R6). Causal mask on tiles tg >= 2J (global
// row/col compare). nch==1 (J<4) writes out directly.
// ---------------------------------------------------------------------------
__global__ __launch_bounds__(512) void attn_part(
    const unsigned short* __restrict__ q, const unsigned short* __restrict__ k,
    const unsigned short* __restrict__ vt, float* __restrict__ pO,
    float* __restrict__ pm, float* __restrict__ pl, float* __restrict__ out)
{
    __shared__ unsigned short Kt[2][64][64];   // [buf][kv][d], swizzled chunks
    __shared__ unsigned short Vt[2][64][64];   // [buf][h][kv], swizzled chunks
    __shared__ unsigned short Ps[8][16][72];   // [wave][q][kv]

    const int bid = blockIdx.x;
    const int b = bid & 3;
    const int J = (bid >> 2) & 31;             // 128-row q-block
    const int c = bid >> 7;                    // kv chunk 0..7
    const int nch = (J + 4) >> 2;              // ceil((J+1)/4)
    if (c >= nch) return;                      // dead block
    const int T = 2 * (J + 1);                 // kv tiles for this q-block
    const int ntile = (T - c * 8 < 8) ? (T - c * 8) : 8;
    const int tg0 = c * 8;

    const int tid  = threadIdx.x;              // 0..511
    const int lane = tid & 63;
    const int w    = tid >> 6;                 // 0..7 (wave owns q rows qb+w*16..+16)
    const int lr   = lane & 15;
    const int lg   = lane >> 4;
    const size_t bq = (size_t)b * NS;
    const int qb = J * 128;

    const int srow = lane >> 3;
    const int schk = (lane & 7) ^ srow;        // pre-swizzled source chunk

    // waves 0-3 stage K (16 rows each), waves 4-7 stage V: 2 instr/wave/tile
    #define STAGEKV(buf, tg)                                                          \
        do {                                                                          \
            int kvb_ = (tg) * 64;                                                     \
            if (w < 4) {                                                              \
                _Pragma("unroll")                                                     \
                for (int i_ = 0; i_ < 2; ++i_) {                                      \
                    int rb_ = w * 16 + i_ * 8;                                        \
                    const unsigned short* src_ =                                      \
                        k + (bq + kvb_ + rb_ + srow) * NH + schk * 8;                 \
                    gload_lds16(src_, &Kt[buf][rb_][0]);                              \
                }                                                                     \
            } else {                                                                  \
                _Pragma("unroll")                                                     \
                for (int i_ = 0; i_ < 2; ++i_) {                                      \
                    int rb_ = (w - 4) * 16 + i_ * 8;                                  \
                    const unsigned short* src_ =                                      \
                        vt + ((size_t)(b * NH + rb_ + srow)) * NS + kvb_ + schk * 8;  \
                    gload_lds16(src_, &Vt[buf][rb_][0]);                              \
                }                                                                     \
            }                                                                         \
        } while (0)

    // Q frags: rows qb + w*16 + lr, used as B-operand
    bf16x8 qf0, qf1;
    {
        const unsigned short* qp = q + (bq + qb + w * 16 + lr) * NH + lg * 8;
        qf0 = *(const bf16x8*)qp;
        qf1 = *(const bf16x8*)(qp + 32);
    }

    f32x4 O[4];                                // O^T: [hf] -> h=hf*16+lg*4+r, q=lr
    #pragma unroll
    for (int i = 0; i < 4; ++i) O[i] = (f32x4){0.f, 0.f, 0.f, 0.f};
    float mrow = -3.0e38f, lsum = 0.f;         // per-lane: q-row = qb + w*16 + lr

    STAGEKV(0, tg0);
    __syncthreads();

    int cur = 0;
    for (int t = 0; t < ntile; ++t) {
        const int tg = tg0 + t;
        STAGEKV(cur ^ 1, (t + 1 < ntile) ? tg + 1 : tg0);

        // S^T = K Q^T: sf[f][r] = S[kv = tg*64 + f*16+lg*4+r][q = qb + w*16+lr]
        f32x4 sf[4];
        #pragma unroll
        for (int f = 0; f < 4; ++f) {
            f32x4 s = (f32x4){0.f, 0.f, 0.f, 0.f};
            int row = f * 16 + lr;
            bf16x8 kb0 = *(const bf16x8*)&Kt[cur][row][((lg    ) ^ (lr & 7)) * 8];
            bf16x8 kb1 = *(const bf16x8*)&Kt[cur][row][((lg + 4) ^ (lr & 7)) * 8];
            s = MFMA16(kb0, qf0, s);
            s = MFMA16(kb1, qf1, s);
            sf[f] = s;
        }

        // causal mask: only tiles tg >= 2J can cross the diagonal
        if (tg >= 2 * J) {
            const int ql = qb + w * 16 + lr;
            #pragma unroll
            for (int f = 0; f < 4; ++f)
                #pragma unroll
                for (int r = 0; r < 4; ++r) {
                    int kvl = tg * 64 + f * 16 + lg * 4 + r;
                    if (kvl > ql) sf[f][r] = -3.0e38f;
                }
        }

        // softmax: lane-local 16-value reduce + 2 shfl
        float pmx = fmaxf(fmaxf(fmaxf(sf[0][0], sf[0][1]), fmaxf(sf[0][2], sf[0][3])),
                          fmaxf(fmaxf(sf[1][0], sf[1][1]), fmaxf(sf[1][2], sf[1][3])));
        float pmx2 = fmaxf(fmaxf(fmaxf(sf[2][0], sf[2][1]), fmaxf(sf[2][2], sf[2][3])),
                           fmaxf(fmaxf(sf[3][0], sf[3][1]), fmaxf(sf[3][2], sf[3][3])));
        pmx = fmaxf(pmx, pmx2);
        pmx = fmaxf(pmx, __shfl_xor(pmx, 16));
        pmx = fmaxf(pmx, __shfl_xor(pmx, 32));
        float mnew = fmaxf(mrow, pmx);
        float corr = __expf(mrow - mnew);
        mrow = mnew;
        float rs = 0.f;
        #pragma unroll
        for (int f = 0; f < 4; ++f)
            #pragma unroll
            for (int r = 0; r < 4; ++r) {
                float p = __expf(sf[f][r] - mnew);
                sf[f][r] = p;
                rs += p;
            }
        rs += __shfl_xor(rs, 16);
        rs += __shfl_xor(rs, 32);
        lsum = lsum * corr + rs;
        #pragma unroll
        for (int hf = 0; hf < 4; ++hf) O[hf] *= corr;

        // P^T via wave-private LDS
        #pragma unroll
        for (int f = 0; f < 4; ++f)
            #pragma unroll
            for (int r = 0; r < 4; ++r)
                Ps[w][lr][f * 16 + lg * 4 + r] = f2bf(sf[f][r]);

        bf16x8 pb0 = *(const bf16x8*)&Ps[w][lr][lg * 8];
        bf16x8 pb1 = *(const bf16x8*)&Ps[w][lr][32 + lg * 8];

        // O^T += V^T P^T
        #pragma unroll
        for (int hf = 0; hf < 4; ++hf) {
            int row = hf * 16 + lr;
            bf16x8 vb0 = *(const bf16x8*)&Vt[cur][row][((lg    ) ^ (lr & 7)) * 8];
            bf16x8 vb1 = *(const bf16x8*)&Vt[cur][row][((lg + 4) ^ (lr & 7)) * 8];
            O[hf] = MFMA16(vb0, pb0, O[hf]);
            O[hf] = MFMA16(vb1, pb1, O[hf]);
        }

        __syncthreads();
        cur ^= 1;
    }

    if (nch == 1) {
        // J < 4: whole causal extent done here — write out directly
        float inv = 1.f / lsum;
        float* op = out + (bq + qb + w * 16 + lr) * NH;
        #pragma unroll
        for (int hf = 0; hf < 4; ++hf) {
            f32x4 o = O[hf] * inv;
            *(f32x4*)&op[hf * 16 + lg * 4] = o;
        }
        return;
    }

    // write partial: prefix(J) = (a+1)(2a+r), J = 4a+r
    const int a4 = J >> 2, r4 = J & 3;
    const int pidx = b * 144 + (a4 + 1) * (2 * a4 + r4) + c;
    float* Po = pO + (size_t)pidx * 8192;
    #pragma unroll
    for (int hf = 0; hf < 4; ++hf)
        *(f32x4*)&Po[(w * 16 + lr) * 64 + hf * 16 + lg * 4] = O[hf];
    if (lane < 16) {
        pm[pidx * 128 + w * 16 + lane] = mrow;
        pl[pidx * 128 + w * 16 + lane] = lsum;
    }
    #undef STAGEKV
}

// ---------------------------------------------------------------------------
// Kernel 3: attention phase B — merge chunk partials, J >= 4 only.
// 112 blocks x 512 thr; thread -> (row 0..127, 16-h slice).
// ---------------------------------------------------------------------------
__global__ __launch_bounds__(512) void attn_merge(
    const float* __restrict__ pO, const float* __restrict__ pm,
    const float* __restrict__ pl, float* __restrict__ out)
{
    const int bid = blockIdx.x;
    const int b = bid & 3, J = 4 + (bid >> 2);
    const int nch = (J + 4) >> 2;
    const int a4 = J >> 2, r4 = J & 3;
    const int pbase = b * 144 + (a4 + 1) * (2 * a4 + r4);
    const int tid = threadIdx.x;
    const int row = tid >> 2, hq = (tid & 3) * 16;

    float M = -3.0e38f, L = 0.f;
    f32x4 acc0 = {0,0,0,0}, acc1 = {0,0,0,0}, acc2 = {0,0,0,0}, acc3 = {0,0,0,0};
    for (int cc = 0; cc < nch; ++cc) {
        int pidx = pbase + cc;
        float mc = pm[pidx * 128 + row];
        float lc = pl[pidx * 128 + row];
        const f32x4* po = (const f32x4*)(pO + (size_t)pidx * 8192 + row * 64 + hq);
        float Mn = fmaxf(M, mc);
        float sO = __expf(M - Mn), sN = __expf(mc - Mn);
        L = L * sO + lc * sN;
        acc0 = acc0 * sO + po[0] * sN;
        acc1 = acc1 * sO + po[1] * sN;
        acc2 = acc2 * sO + po[2] * sN;
        acc3 = acc3 * sO + po[3] * sN;
        M = Mn;
    }
    float inv = 1.f / L;
    float* op = out + ((size_t)b * NS + (size_t)J * 128 + row) * NH + hq;
    *(f32x4*)(op + 0)  = acc0 * inv;
    *(f32x4*)(op + 4)  = acc1 * inv;
    *(f32x4*)(op + 8)  = acc2 * inv;
    *(f32x4*)(op + 12) = acc3 * inv;
}

extern "C" void kernel_launch(void* const* d_in, const int* in_sizes, int n_in,
                              void* d_out, int out_size, void* d_ws, size_t ws_size,
                              hipStream_t stream)
{
    const float* x  = (const float*)d_in[0];
    const float* Wq = (const float*)d_in[1];
    const float* Wk = (const float*)d_in[2];
    const float* Wv = (const float*)d_in[3];
    float* out = (float*)d_out;

    const size_t n = (size_t)NB * NS * NH;            // 1,048,576 elements
    unsigned short* qb_ = (unsigned short*)d_ws;      // 2 MB
    unsigned short* kb_ = qb_ + n;                    // 2 MB
    unsigned short* vT  = kb_ + n;                    // 2 MB (layout [b][h][s])
    unsigned short* wT  = vT + n;                     // 384 KB (layout [192][1024])
    float* pO  = (float*)(wT + 192 * 1024);           // 576 x 8192 f32 = 18.9 MB
    float* pm_ = pO + (size_t)576 * 8192;             // 576 x 128 f32
    float* pl_ = pm_ + 576 * 128;                     // 576 x 128 f32

    wconv<<<dim3(192), dim3(256), 0, stream>>>(Wq, Wk, Wv, wT);
    qkv_proj<<<dim3(512), dim3(512), 0, stream>>>(x, wT, qb_, kb_, vT);
    attn_part<<<dim3(1024), dim3(512), 0, stream>>>(qb_, kb_, vT, pO, pm_, pl_, out);
    attn_merge<<<dim3(112), dim3(512), 0, stream>>>(pO, pm_, pl_, out);
}

// Round 19
// 62.931 us; speedup vs baseline: 1.0313x; 1.0313x over previous
//
#include <hip/hip_runtime.h>

typedef __attribute__((ext_vector_type(8))) short bf16x8;
typedef __attribute__((ext_vector_type(4))) short bf16x4;
typedef __attribute__((ext_vector_type(4))) float f32x4;

#define MFMA16(A, Bv, C) __builtin_amdgcn_mfma_f32_16x16x32_bf16((A), (Bv), (C), 0, 0, 0)

static constexpr int NB = 4, NS = 4096, ND = 1024, NH = 64;

__device__ __forceinline__ unsigned short f2bf(float f) {
    union { float f; unsigned int u; } x; x.f = f;
    unsigned int r = x.u + 0x7fffu + ((x.u >> 16) & 1u);
    return (unsigned short)(r >> 16);
}

// async global->LDS, 16B per lane; LDS dest = wave-uniform base + lane*16
__device__ __forceinline__ void gload_lds16(const void* g, void* l) {
    __builtin_amdgcn_global_load_lds((const __attribute__((address_space(1))) void*)g,
                                     (__attribute__((address_space(3))) void*)l, 16, 0, 0);
}

// ---------------------------------------------------------------------------
// Kernel 0: W[D][H] fp32 -> wT[m*64+n][k] bf16  (192 x 1024, 384 KB, L2-hot)
// ---------------------------------------------------------------------------
__global__ __launch_bounds__(256) void wconv(
    const float* __restrict__ Wq, const float* __restrict__ Wk,
    const float* __restrict__ Wv, unsigned short* __restrict__ wT)
{
    int mn = blockIdx.x;                 // 0..191 = m*64 + n
    int m = mn >> 6, n = mn & 63;
    const float* W = (m == 0) ? Wq : (m == 1) ? Wk : Wv;
    unsigned short* dst = wT + (size_t)mn * ND;
    for (int k = threadIdx.x; k < ND; k += 256)
        dst[k] = f2bf(W[(size_t)k * NH + n]);
}

// ---------------------------------------------------------------------------
// Kernel 1: QKV projection — R9 structure + DRAM-burst x lane map.
// ONLY change vs the 64.06us baseline: LOADX lane map xrow=tid>>4, xcg=tid&15
// (16 consecutive lanes = 256B contiguous per row; was 64 scattered 16B
// requests at 4KB stride). Pipeline/coverage/Xs layout unchanged.
// ---------------------------------------------------------------------------
__global__ __launch_bounds__(512) void qkv_proj(
    const float* __restrict__ x, const unsigned short* __restrict__ wT,
    unsigned short* __restrict__ qo, unsigned short* __restrict__ ko,
    unsigned short* __restrict__ vt)
{
    __shared__ unsigned short Ws[2][192][64];   // [buf][n][k], XOR-swizzled chunks
    __shared__ unsigned short Xs[2][32][72];    // [buf][m][k], +8 pad
    __shared__ unsigned short Ls[32][72];       // v transpose staging

    const int tid  = threadIdx.x;               // 0..511
    const int lane = tid & 63;
    const int w    = tid >> 6;                  // 0..7
    const int lr   = lane & 15;
    const int lg   = lane >> 4;
    const int mg   = w >> 2;                    // M half (16 rows)
    const int cg   = w & 3;                     // N quarter (48 cols)
    const int mbase = blockIdx.x * 32;

    // W stage: instr = 8 rows x 128B; LDS[r][c] holds src[r][c ^ (r&7)]
    const int wr8 = lane >> 3;
    const int wck = (lane & 7) ^ wr8;
    // x: DRAM-burst map — thread -> (row = tid>>4, float4 slot = tid&15);
    // 16 consecutive lanes cover 256B contiguous of one row.
    const int xrow = tid >> 4;                  // 0..31
    const int xcg  = tid & 15;                  // 0..15

    f32x4 acc[3];
    #pragma unroll
    for (int f = 0; f < 3; ++f) acc[f] = (f32x4){0.f, 0.f, 0.f, 0.f};

    const float* xsrc = x + (size_t)(mbase + xrow) * ND + xcg * 4;

    #define STAGE_W(buf, kb)                                                         \
        do {                                                                         \
            _Pragma("unroll")                                                        \
            for (int i_ = 0; i_ < 3; ++i_) {                                         \
                int rb_ = w * 24 + i_ * 8;                                           \
                gload_lds16(wT + (size_t)(rb_ + wr8) * ND + (kb) + wck * 8,          \
                            &Ws[buf][rb_][0]);                                       \
            }                                                                        \
        } while (0)

    #define LOADX(kb) do { xr = *(const float4*)(xsrc + (kb)); } while (0)

    #define WRITEX(buf)                                                              \
        do {                                                                         \
            bf16x4 p_;                                                               \
            p_[0] = (short)f2bf(xr.x); p_[1] = (short)f2bf(xr.y);                    \
            p_[2] = (short)f2bf(xr.z); p_[3] = (short)f2bf(xr.w);                    \
            *(bf16x4*)&Xs[buf][xrow][xcg * 4] = p_;                                  \
        } while (0)

    float4 xr;
    STAGE_W(0, 0);
    LOADX(0);
    WRITEX(0);
    __syncthreads();

    for (int kt = 0; kt < 16; ++kt) {
        const int cur = kt & 1;
        if (kt + 1 < 16) {
            STAGE_W(cur ^ 1, (kt + 1) * 64);
            LOADX((kt + 1) * 64);
        }

        #pragma unroll
        for (int kk = 0; kk < 2; ++kk) {
            bf16x8 af = *(const bf16x8*)&Xs[cur][mg * 16 + lr][(kk * 4 + lg) * 8];
            #pragma unroll
            for (int f = 0; f < 3; ++f) {
                int row = cg * 48 + f * 16 + lr;
                bf16x8 bfr = *(const bf16x8*)&Ws[cur][row][((kk * 4 + lg) ^ (lr & 7)) * 8];
                acc[f] = MFMA16(af, bfr, acc[f]);
            }
        }

        if (kt + 1 < 16) WRITEX(cur ^ 1);   // Xs[next]: readers done a barrier ago
        __syncthreads();
    }

    // epilogue: frag (cg,f) -> n-block b16 = cg*3+f (16 cols, inside one of q/k/v)
    #pragma unroll
    for (int f = 0; f < 3; ++f) {
        int b16 = cg * 3 + f;
        int sel = b16 >> 2;
        int col = (b16 & 3) * 16 + lr;
        #pragma unroll
        for (int rr = 0; rr < 4; ++rr) {
            int mrow = mg * 16 + lg * 4 + rr;       // C/D: row=(lane>>4)*4+reg
            float v = acc[f][rr];
            if (sel == 0)
                qo[(size_t)(mbase + mrow) * NH + col] = f2bf(v * 0.125f);
            else if (sel == 1)
                ko[(size_t)(mbase + mrow) * NH + col] = f2bf(v);
            else
                Ls[mrow][col] = f2bf(v);
        }
    }
    __syncthreads();
    {   // transpose 32 s x 64 h: thread -> (h = tid>>3, 4-s strip)
        int h  = tid >> 3;                          // 0..63
        int s4 = (tid & 7) * 4;                     // 0..28
        bf16x4 v0;
        #pragma unroll
        for (int jj = 0; jj < 4; ++jj) v0[jj] = (short)Ls[s4 + jj][h];
        int b_ = mbase >> 12;
        int sb = (mbase & (NS - 1)) + s4;
        *(bf16x4*)(vt + ((size_t)(b_ * NH + h)) * NS + sb) = v0;
    }
    #undef STAGE_W
    #undef LOADX
    #undef WRITEX
}

// ---------------------------------------------------------------------------
// Kernel 2: attention phase A — QBLK=64 (R16 best), 2-slot staging +
// swapped-operand math. nch==1 blocks (j<8) write out directly.
// ---------------------------------------------------------------------------
__global__ __launch_bounds__(256) void attn_part(
    const unsigned short* __restrict__ q, const unsigned short* __restrict__ k,
    const unsigned short* __restrict__ vt, float* __restrict__ pO,
    float* __restrict__ pm, float* __restrict__ pl, float* __restrict__ out)
{
    __shared__ unsigned short Kt[2][64][64];   // [buf][kv][d], swizzled chunks
    __shared__ unsigned short Vt[2][64][64];   // [buf][h][kv], swizzled chunks
    __shared__ unsigned short Ps[4][16][72];   // [wave][q][kv]

    const int bid = blockIdx.x;
    const int b = bid & 3;
    const int j = (bid >> 2) & 63;
    const int c = bid >> 8;                    // 0..7
    if (c > (j >> 3)) return;                  // dead block (beyond causal extent)
    const int nch = (j >> 3) + 1;
    const int ntile = (j + 1 - c * 8 < 8) ? (j + 1 - c * 8) : 8;
    const int tg0 = c * 8;

    const int tid  = threadIdx.x;
    const int lane = tid & 63;
    const int w    = tid >> 6;
    const int lr   = lane & 15;
    const int lg   = lane >> 4;
    const size_t bq = (size_t)b * NS;
    const int qb = j * 64;

    const int srow = lane >> 3;
    const int schk = (lane & 7) ^ srow;        // pre-swizzled source chunk

    #define STAGEKV(buf, tg)                                                          \
        do {                                                                          \
            int kvb_ = (tg) * 64;                                                     \
            if (w < 2) {                                                              \
                _Pragma("unroll")                                                     \
                for (int i_ = 0; i_ < 4; ++i_) {                                      \
                    int rb_ = w * 32 + i_ * 8;                                        \
                    const unsigned short* src_ =                                      \
                        k + (bq + kvb_ + rb_ + srow) * NH + schk * 8;                 \
                    gload_lds16(src_, &Kt[buf][rb_][0]);                              \
                }                                                                     \
            } else {                                                                  \
                _Pragma("unroll")                                                     \
                for (int i_ = 0; i_ < 4; ++i_) {                                      \
                    int rb_ = (w - 2) * 32 + i_ * 8;                                  \
                    const unsigned short* src_ =                                      \
                        vt + ((size_t)(b * NH + rb_ + srow)) * NS + kvb_ + schk * 8;  \
                    gload_lds16(src_, &Vt[buf][rb_][0]);                              \
                }                                                                     \
            }                                                                         \
        } while (0)

    // Q frags: rows qb + w*16 + lr, used as B-operand
    bf16x8 qf0, qf1;
    {
        const unsigned short* qp = q + (bq + qb + w * 16 + lr) * NH + lg * 8;
        qf0 = *(const bf16x8*)qp;
        qf1 = *(const bf16x8*)(qp + 32);
    }

    f32x4 O[4];                                // O^T: [hf] -> h=hf*16+lg*4+r, q=lr
    #pragma unroll
    for (int i = 0; i < 4; ++i) O[i] = (f32x4){0.f, 0.f, 0.f, 0.f};
    float mrow = -3.0e38f, lsum = 0.f;         // per-lane: q-row = w*16+lr

    STAGEKV(0, tg0);
    __syncthreads();

    int cur = 0;
    for (int t = 0; t < ntile; ++t) {
        const int tg = tg0 + t;
        STAGEKV(cur ^ 1, (t + 1 < ntile) ? tg + 1 : tg0);

        // S^T = K Q^T: sf[f][r] = S[kv = f*16+lg*4+r][q = w*16+lr]
        f32x4 sf[4];
        #pragma unroll
        for (int f = 0; f < 4; ++f) {
            f32x4 s = (f32x4){0.f, 0.f, 0.f, 0.f};
            int row = f * 16 + lr;
            bf16x8 kb0 = *(const bf16x8*)&Kt[cur][row][((lg    ) ^ (lr & 7)) * 8];
            bf16x8 kb1 = *(const bf16x8*)&Kt[cur][row][((lg + 4) ^ (lr & 7)) * 8];
            s = MFMA16(kb0, qf0, s);
            s = MFMA16(kb1, qf1, s);
            sf[f] = s;
        }

        if (tg == j) {
            #pragma unroll
            for (int f = 0; f < 4; ++f)
                #pragma unroll
                for (int r = 0; r < 4; ++r) {
                    int kvl = f * 16 + lg * 4 + r;
                    int ql  = w * 16 + lr;
                    if (kvl > ql) sf[f][r] = -3.0e38f;
                }
        }

        // softmax: lane-local 16-value reduce + 2 shfl
        float pmx = fmaxf(fmaxf(fmaxf(sf[0][0], sf[0][1]), fmaxf(sf[0][2], sf[0][3])),
                          fmaxf(fmaxf(sf[1][0], sf[1][1]), fmaxf(sf[1][2], sf[1][3])));
        float pmx2 = fmaxf(fmaxf(fmaxf(sf[2][0], sf[2][1]), fmaxf(sf[2][2], sf[2][3])),
                           fmaxf(fmaxf(sf[3][0], sf[3][1]), fmaxf(sf[3][2], sf[3][3])));
        pmx = fmaxf(pmx, pmx2);
        pmx = fmaxf(pmx, __shfl_xor(pmx, 16));
        pmx = fmaxf(pmx, __shfl_xor(pmx, 32));
        float mnew = fmaxf(mrow, pmx);
        float corr = __expf(mrow - mnew);
        mrow = mnew;
        float rs = 0.f;
        #pragma unroll
        for (int f = 0; f < 4; ++f)
            #pragma unroll
            for (int r = 0; r < 4; ++r) {
                float p = __expf(sf[f][r] - mnew);
                sf[f][r] = p;
                rs += p;
            }
        rs += __shfl_xor(rs, 16);
        rs += __shfl_xor(rs, 32);
        lsum = lsum * corr + rs;
        #pragma unroll
        for (int hf = 0; hf < 4; ++hf) O[hf] *= corr;

        // P^T via wave-private LDS
        #pragma unroll
        for (int f = 0; f < 4; ++f)
            #pragma unroll
            for (int r = 0; r < 4; ++r)
                Ps[w][lr][f * 16 + lg * 4 + r] = f2bf(sf[f][r]);

        bf16x8 pb0 = *(const bf16x8*)&Ps[w][lr][lg * 8];
        bf16x8 pb1 = *(const bf16x8*)&Ps[w][lr][32 + lg * 8];

        // O^T += V^T P^T
        #pragma unroll
        for (int hf = 0; hf < 4; ++hf) {
            int row = hf * 16 + lr;
            bf16x8 vb0 = *(const bf16x8*)&Vt[cur][row][((lg    ) ^ (lr & 7)) * 8];
            bf16x8 vb1 = *(const bf16x8*)&Vt[cur][row][((lg + 4) ^ (lr & 7)) * 8];
            O[hf] = MFMA16(vb0, pb0, O[hf]);
            O[hf] = MFMA16(vb1, pb1, O[hf]);
        }

        __syncthreads();
        cur ^= 1;
    }

    if (nch == 1) {
        // j < 8: whole causal extent done here — write out directly
        float inv = 1.f / lsum;
        float* op = out + (bq + qb + w * 16 + lr) * NH;
        #pragma unroll
        for (int hf = 0; hf < 4; ++hf) {
            f32x4 o = O[hf] * inv;
            *(f32x4*)&op[hf * 16 + lg * 4] = o;
        }
        return;
    }

    const int a8 = j >> 3, r8 = j & 7;
    const int pidx = b * 288 + (a8 + 1) * (4 * a8 + r8) + c;
    float* Po = pO + (size_t)pidx * 4096;
    #pragma unroll
    for (int hf = 0; hf < 4; ++hf)
        *(f32x4*)&Po[(w * 16 + lr) * 64 + hf * 16 + lg * 4] = O[hf];
    if (lane < 16) {
        pm[pidx * 64 + w * 16 + lane] = mrow;
        pl[pidx * 64 + w * 16 + lane] = lsum;
    }
    #undef STAGEKV
}

// ---------------------------------------------------------------------------
// Kernel 3: attention phase B — merge chunk partials, j >= 8 only (224 blocks).
// ---------------------------------------------------------------------------
__global__ __launch_bounds__(256) void attn_merge(
    const float* __restrict__ pO, const float* __restrict__ pm,
    const float* __restrict__ pl, float* __restrict__ out)
{
    const int bid = blockIdx.x;
    const int b = bid & 3, j = 8 + (bid >> 2);
    const int nch = (j >> 3) + 1;
    const int a8 = j >> 3, r8 = j & 7;
    const int pbase = b * 288 + (a8 + 1) * (4 * a8 + r8);
    const int tid = threadIdx.x;
    const int row = tid >> 2, hq = (tid & 3) * 16;

    float M = -3.0e38f, L = 0.f;
    f32x4 acc0 = {0,0,0,0}, acc1 = {0,0,0,0}, acc2 = {0,0,0,0}, acc3 = {0,0,0,0};
    for (int cc = 0; cc < nch; ++cc) {
        int pidx = pbase + cc;
        float mc = pm[pidx * 64 + row];
        float lc = pl[pidx * 64 + row];
        const f32x4* po = (const f32x4*)(pO + (size_t)pidx * 4096 + row * 64 + hq);
        float Mn = fmaxf(M, mc);
        float sO = __expf(M - Mn), sN = __expf(mc - Mn);
        L = L * sO + lc * sN;
        acc0 = acc0 * sO + po[0] * sN;
        acc1 = acc1 * sO + po[1] * sN;
        acc2 = acc2 * sO + po[2] * sN;
        acc3 = acc3 * sO + po[3] * sN;
        M = Mn;
    }
    float inv = 1.f / L;
    float* op = out + ((size_t)b * NS + (size_t)j * 64 + row) * NH + hq;
    *(f32x4*)(op + 0)  = acc0 * inv;
    *(f32x4*)(op + 4)  = acc1 * inv;
    *(f32x4*)(op + 8)  = acc2 * inv;
    *(f32x4*)(op + 12) = acc3 * inv;
}

extern "C" void kernel_launch(void* const* d_in, const int* in_sizes, int n_in,
                              void* d_out, int out_size, void* d_ws, size_t ws_size,
                              hipStream_t stream)
{
    const float* x  = (const float*)d_in[0];
    const float* Wq = (const float*)d_in[1];
    const float* Wk = (const float*)d_in[2];
    const float* Wv = (const float*)d_in[3];
    float* out = (float*)d_out;

    const size_t n = (size_t)NB * NS * NH;            // 1,048,576 elements
    unsigned short* qb_ = (unsigned short*)d_ws;      // 2 MB
    unsigned short* kb_ = qb_ + n;                    // 2 MB
    unsigned short* vT  = kb_ + n;                    // 2 MB (layout [b][h][s])
    unsigned short* wT  = vT + n;                     // 384 KB (layout [192][1024])
    float* pO  = (float*)(wT + 192 * 1024);           // 1152 x 4096 f32 = 18.9 MB
    float* pm_ = pO + (size_t)1152 * 4096;            // 1152 x 64 f32
    float* pl_ = pm_ + 1152 * 64;                     // 1152 x 64 f32

    wconv<<<dim3(192), dim3(256), 0, stream>>>(Wq, Wk, Wv, wT);
    qkv_proj<<<dim3(512), dim3(512), 0, stream>>>(x, wT, qb_, kb_, vT);
    attn_part<<<dim3(2048), dim3(256), 0, stream>>>(qb_, kb_, vT, pO, pm_, pl_, out);
    attn_merge<<<dim3(224), dim3(256), 0, stream>>>(pO, pm_, pl_, out);
}

// Round 20
// 62.445 us; speedup vs baseline: 1.0393x; 1.0078x over previous
//
#include <hip/hip_runtime.h>

typedef __attribute__((ext_vector_type(8))) short bf16x8;
typedef __attribute__((ext_vector_type(4))) short bf16x4;
typedef __attribute__((ext_vector_type(4))) float f32x4;

#define MFMA16(A, Bv, C) __builtin_amdgcn_mfma_f32_16x16x32_bf16((A), (Bv), (C), 0, 0, 0)

static constexpr int NB = 4, NS = 4096, ND = 1024, NH = 64;

__device__ __forceinline__ unsigned short f2bf(float f) {
    union { float f; unsigned int u; } x; x.f = f;
    unsigned int r = x.u + 0x7fffu + ((x.u >> 16) & 1u);
    return (unsigned short)(r >> 16);
}
__device__ __forceinline__ float bf2f(unsigned short u) {
    union { unsigned int u; float f; } x; x.u = ((unsigned int)u) << 16;
    return x.f;
}

// async global->LDS, 16B per lane; LDS dest = wave-uniform base + lane*16
__device__ __forceinline__ void gload_lds16(const void* g, void* l) {
    __builtin_amdgcn_global_load_lds((const __attribute__((address_space(1))) void*)g,
                                     (__attribute__((address_space(3))) void*)l, 16, 0, 0);
}

// ---------------------------------------------------------------------------
// Kernel 0: W[D][H] fp32 -> wT[m*64+n][k] bf16 via coalesced reads + LDS
// transpose. 48 blocks (m, 64-k block) x 256 thr; 64B/thread contiguous read
// (vs old 1024 stride-256B scalar reads per block).
// ---------------------------------------------------------------------------
__global__ __launch_bounds__(256) void wconv(
    const float* __restrict__ Wq, const float* __restrict__ Wk,
    const float* __restrict__ Wv, unsigned short* __restrict__ wT)
{
    __shared__ unsigned short T[64][72];        // [n][k] for this k-block

    const int bidx = blockIdx.x;                // 0..47 = m*16 + kb16
    const int m  = bidx >> 4;
    const int kb = (bidx & 15) * 64;
    const float* W = (m == 0) ? Wq : (m == 1) ? Wk : Wv;
    const int tid = threadIdx.x;

    {   // read 64 k-rows x 64 n coalesced: thread -> (k-row, 16-col group)
        int row = tid >> 2;
        int c16 = (tid & 3) * 16;
        const float* src = W + (size_t)(kb + row) * NH + c16;
        float4 u0 = *(const float4*)src;
        float4 u1 = *(const float4*)(src + 4);
        float4 u2 = *(const float4*)(src + 8);
        float4 u3 = *(const float4*)(src + 12);
        T[c16 +  0][row] = f2bf(u0.x); T[c16 +  1][row] = f2bf(u0.y);
        T[c16 +  2][row] = f2bf(u0.z); T[c16 +  3][row] = f2bf(u0.w);
        T[c16 +  4][row] = f2bf(u1.x); T[c16 +  5][row] = f2bf(u1.y);
        T[c16 +  6][row] = f2bf(u1.z); T[c16 +  7][row] = f2bf(u1.w);
        T[c16 +  8][row] = f2bf(u2.x); T[c16 +  9][row] = f2bf(u2.y);
        T[c16 + 10][row] = f2bf(u2.z); T[c16 + 11][row] = f2bf(u2.w);
        T[c16 + 12][row] = f2bf(u3.x); T[c16 + 13][row] = f2bf(u3.y);
        T[c16 + 14][row] = f2bf(u3.z); T[c16 + 15][row] = f2bf(u3.w);
    }
    __syncthreads();
    {   // write wT[m*64+n][kb..kb+64]: thread -> (n, 16-k group), 32B each
        int n  = tid >> 2;
        int kc = (tid & 3) * 16;
        bf16x8 v0 = *(const bf16x8*)&T[n][kc];
        bf16x8 v1 = *(const bf16x8*)&T[n][kc + 8];
        unsigned short* dst = wT + (size_t)(m * 64 + n) * ND + kb + kc;
        *(bf16x8*)dst       = v0;
        *(bf16x8*)(dst + 8) = v1;
    }
}

// ---------------------------------------------------------------------------
// Kernel 1: QKV projection — R19 config verbatim (best: ~24 us).
// 512 blocks x 512 thr (8 waves), M32 x N192, BK=64, 16 steps, 2 blocks/CU,
// DRAM-burst x lane map (xrow=tid>>4, xcg=tid&15).
// ---------------------------------------------------------------------------
__global__ __launch_bounds__(512) void qkv_proj(
    const float* __restrict__ x, const unsigned short* __restrict__ wT,
    unsigned short* __restrict__ qo, unsigned short* __restrict__ ko,
    unsigned short* __restrict__ vt)
{
    __shared__ unsigned short Ws[2][192][64];   // [buf][n][k], XOR-swizzled chunks
    __shared__ unsigned short Xs[2][32][72];    // [buf][m][k], +8 pad
    __shared__ unsigned short Ls[32][72];       // v transpose staging

    const int tid  = threadIdx.x;               // 0..511
    const int lane = tid & 63;
    const int w    = tid >> 6;                  // 0..7
    const int lr   = lane & 15;
    const int lg   = lane >> 4;
    const int mg   = w >> 2;                    // M half (16 rows)
    const int cg   = w & 3;                     // N quarter (48 cols)
    const int mbase = blockIdx.x * 32;

    // W stage: instr = 8 rows x 128B; LDS[r][c] holds src[r][c ^ (r&7)]
    const int wr8 = lane >> 3;
    const int wck = (lane & 7) ^ wr8;
    // x: DRAM-burst map — 16 consecutive lanes cover 256B contiguous per row
    const int xrow = tid >> 4;                  // 0..31
    const int xcg  = tid & 15;                  // 0..15

    f32x4 acc[3];
    #pragma unroll
    for (int f = 0; f < 3; ++f) acc[f] = (f32x4){0.f, 0.f, 0.f, 0.f};

    const float* xsrc = x + (size_t)(mbase + xrow) * ND + xcg * 4;

    #define STAGE_W(buf, kb)                                                         \
        do {                                                                         \
            _Pragma("unroll")                                                        \
            for (int i_ = 0; i_ < 3; ++i_) {                                         \
                int rb_ = w * 24 + i_ * 8;                                           \
                gload_lds16(wT + (size_t)(rb_ + wr8) * ND + (kb) + wck * 8,          \
                            &Ws[buf][rb_][0]);                                       \
            }                                                                        \
        } while (0)

    #define LOADX(kb) do { xr = *(const float4*)(xsrc + (kb)); } while (0)

    #define WRITEX(buf)                                                              \
        do {                                                                         \
            bf16x4 p_;                                                               \
            p_[0] = (short)f2bf(xr.x); p_[1] = (short)f2bf(xr.y);                    \
            p_[2] = (short)f2bf(xr.z); p_[3] = (short)f2bf(xr.w);                    \
            *(bf16x4*)&Xs[buf][xrow][xcg * 4] = p_;                                  \
        } while (0)

    float4 xr;
    STAGE_W(0, 0);
    LOADX(0);
    WRITEX(0);
    __syncthreads();

    for (int kt = 0; kt < 16; ++kt) {
        const int cur = kt & 1;
        if (kt + 1 < 16) {
            STAGE_W(cur ^ 1, (kt + 1) * 64);
            LOADX((kt + 1) * 64);
        }

        #pragma unroll
        for (int kk = 0; kk < 2; ++kk) {
            bf16x8 af = *(const bf16x8*)&Xs[cur][mg * 16 + lr][(kk * 4 + lg) * 8];
            #pragma unroll
            for (int f = 0; f < 3; ++f) {
                int row = cg * 48 + f * 16 + lr;
                bf16x8 bfr = *(const bf16x8*)&Ws[cur][row][((kk * 4 + lg) ^ (lr & 7)) * 8];
                acc[f] = MFMA16(af, bfr, acc[f]);
            }
        }

        if (kt + 1 < 16) WRITEX(cur ^ 1);   // Xs[next]: readers done a barrier ago
        __syncthreads();
    }

    // epilogue: frag (cg,f) -> n-block b16 = cg*3+f (16 cols, inside one of q/k/v)
    #pragma unroll
    for (int f = 0; f < 3; ++f) {
        int b16 = cg * 3 + f;
        int sel = b16 >> 2;
        int col = (b16 & 3) * 16 + lr;
        #pragma unroll
        for (int rr = 0; rr < 4; ++rr) {
            int mrow = mg * 16 + lg * 4 + rr;       // C/D: row=(lane>>4)*4+reg
            float v = acc[f][rr];
            if (sel == 0)
                qo[(size_t)(mbase + mrow) * NH + col] = f2bf(v * 0.125f);
            else if (sel == 1)
                ko[(size_t)(mbase + mrow) * NH + col] = f2bf(v);
            else
                Ls[mrow][col] = f2bf(v);
        }
    }
    __syncthreads();
    {   // transpose 32 s x 64 h: thread -> (h = tid>>3, 4-s strip)
        int h  = tid >> 3;                          // 0..63
        int s4 = (tid & 7) * 4;                     // 0..28
        bf16x4 v0;
        #pragma unroll
        for (int jj = 0; jj < 4; ++jj) v0[jj] = (short)Ls[s4 + jj][h];
        int b_ = mbase >> 12;
        int sb = (mbase & (NS - 1)) + s4;
        *(bf16x4*)(vt + ((size_t)(b_ * NH + h)) * NS + sb) = v0;
    }
    #undef STAGE_W
    #undef LOADX
    #undef WRITEX
}

// ---------------------------------------------------------------------------
// Kernel 2: attention phase A — QBLK=64, 2-slot staging + swapped-operand
// math. Partials now BF16 (halves pO round-trip traffic; error budget OK).
// nch==1 blocks (j<8) write out directly.
// ---------------------------------------------------------------------------
__global__ __launch_bounds__(256) void attn_part(
    const unsigned short* __restrict__ q, const unsigned short* __restrict__ k,
    const unsigned short* __restrict__ vt, unsigned short* __restrict__ pO,
    float* __restrict__ pm, float* __restrict__ pl, float* __restrict__ out)
{
    __shared__ unsigned short Kt[2][64][64];   // [buf][kv][d], swizzled chunks
    __shared__ unsigned short Vt[2][64][64];   // [buf][h][kv], swizzled chunks
    __shared__ unsigned short Ps[4][16][72];   // [wave][q][kv]

    const int bid = blockIdx.x;
    const int b = bid & 3;
    const int j = (bid >> 2) & 63;
    const int c = bid >> 8;                    // 0..7
    if (c > (j >> 3)) return;                  // dead block (beyond causal extent)
    const int nch = (j >> 3) + 1;
    const int ntile = (j + 1 - c * 8 < 8) ? (j + 1 - c * 8) : 8;
    const int tg0 = c * 8;

    const int tid  = threadIdx.x;
    const int lane = tid & 63;
    const int w    = tid >> 6;
    const int lr   = lane & 15;
    const int lg   = lane >> 4;
    const size_t bq = (size_t)b * NS;
    const int qb = j * 64;

    const int srow = lane >> 3;
    const int schk = (lane & 7) ^ srow;        // pre-swizzled source chunk

    #define STAGEKV(buf, tg)                                                          \
        do {                                                                          \
            int kvb_ = (tg) * 64;                                                     \
            if (w < 2) {                                                              \
                _Pragma("unroll")                                                     \
                for (int i_ = 0; i_ < 4; ++i_) {                                      \
                    int rb_ = w * 32 + i_ * 8;                                        \
                    const unsigned short* src_ =                                      \
                        k + (bq + kvb_ + rb_ + srow) * NH + schk * 8;                 \
                    gload_lds16(src_, &Kt[buf][rb_][0]);                              \
                }                                                                     \
            } else {                                                                  \
                _Pragma("unroll")                                                     \
                for (int i_ = 0; i_ < 4; ++i_) {                                      \
                    int rb_ = (w - 2) * 32 + i_ * 8;                                  \
                    const unsigned short* src_ =                                      \
                        vt + ((size_t)(b * NH + rb_ + srow)) * NS + kvb_ + schk * 8;  \
                    gload_lds16(src_, &Vt[buf][rb_][0]);                              \
                }                                                                     \
            }                                                                         \
        } while (0)

    // Q frags: rows qb + w*16 + lr, used as B-operand
    bf16x8 qf0, qf1;
    {
        const unsigned short* qp = q + (bq + qb + w * 16 + lr) * NH + lg * 8;
        qf0 = *(const bf16x8*)qp;
        qf1 = *(const bf16x8*)(qp + 32);
    }

    f32x4 O[4];                                // O^T: [hf] -> h=hf*16+lg*4+r, q=lr
    #pragma unroll
    for (int i = 0; i < 4; ++i) O[i] = (f32x4){0.f, 0.f, 0.f, 0.f};
    float mrow = -3.0e38f, lsum = 0.f;         // per-lane: q-row = w*16+lr

    STAGEKV(0, tg0);
    __syncthreads();

    int cur = 0;
    for (int t = 0; t < ntile; ++t) {
        const int tg = tg0 + t;
        STAGEKV(cur ^ 1, (t + 1 < ntile) ? tg + 1 : tg0);

        // S^T = K Q^T: sf[f][r] = S[kv = f*16+lg*4+r][q = w*16+lr]
        f32x4 sf[4];
        #pragma unroll
        for (int f = 0; f < 4; ++f) {
            f32x4 s = (f32x4){0.f, 0.f, 0.f, 0.f};
            int row = f * 16 + lr;
            bf16x8 kb0 = *(const bf16x8*)&Kt[cur][row][((lg    ) ^ (lr & 7)) * 8];
            bf16x8 kb1 = *(const bf16x8*)&Kt[cur][row][((lg + 4) ^ (lr & 7)) * 8];
            s = MFMA16(kb0, qf0, s);
            s = MFMA16(kb1, qf1, s);
            sf[f] = s;
        }

        if (tg == j) {
            #pragma unroll
            for (int f = 0; f < 4; ++f)
                #pragma unroll
                for (int r = 0; r < 4; ++r) {
                    int kvl = f * 16 + lg * 4 + r;
                    int ql  = w * 16 + lr;
                    if (kvl > ql) sf[f][r] = -3.0e38f;
                }
        }

        // softmax: lane-local 16-value reduce + 2 shfl
        float pmx = fmaxf(fmaxf(fmaxf(sf[0][0], sf[0][1]), fmaxf(sf[0][2], sf[0][3])),
                          fmaxf(fmaxf(sf[1][0], sf[1][1]), fmaxf(sf[1][2], sf[1][3])));
        float pmx2 = fmaxf(fmaxf(fmaxf(sf[2][0], sf[2][1]), fmaxf(sf[2][2], sf[2][3])),
                           fmaxf(fmaxf(sf[3][0], sf[3][1]), fmaxf(sf[3][2], sf[3][3])));
        pmx = fmaxf(pmx, pmx2);
        pmx = fmaxf(pmx, __shfl_xor(pmx, 16));
        pmx = fmaxf(pmx, __shfl_xor(pmx, 32));
        float mnew = fmaxf(mrow, pmx);
        float corr = __expf(mrow - mnew);
        mrow = mnew;
        float rs = 0.f;
        #pragma unroll
        for (int f = 0; f < 4; ++f)
            #pragma unroll
            for (int r = 0; r < 4; ++r) {
                float p = __expf(sf[f][r] - mnew);
                sf[f][r] = p;
                rs += p;
            }
        rs += __shfl_xor(rs, 16);
        rs += __shfl_xor(rs, 32);
        lsum = lsum * corr + rs;
        #pragma unroll
        for (int hf = 0; hf < 4; ++hf) O[hf] *= corr;

        // P^T via wave-private LDS
        #pragma unroll
        for (int f = 0; f < 4; ++f)
            #pragma unroll
            for (int r = 0; r < 4; ++r)
                Ps[w][lr][f * 16 + lg * 4 + r] = f2bf(sf[f][r]);

        bf16x8 pb0 = *(const bf16x8*)&Ps[w][lr][lg * 8];
        bf16x8 pb1 = *(const bf16x8*)&Ps[w][lr][32 + lg * 8];

        // O^T += V^T P^T
        #pragma unroll
        for (int hf = 0; hf < 4; ++hf) {
            int row = hf * 16 + lr;
            bf16x8 vb0 = *(const bf16x8*)&Vt[cur][row][((lg    ) ^ (lr & 7)) * 8];
            bf16x8 vb1 = *(const bf16x8*)&Vt[cur][row][((lg + 4) ^ (lr & 7)) * 8];
            O[hf] = MFMA16(vb0, pb0, O[hf]);
            O[hf] = MFMA16(vb1, pb1, O[hf]);
        }

        __syncthreads();
        cur ^= 1;
    }

    if (nch == 1) {
        // j < 8: whole causal extent done here — write out directly
        float inv = 1.f / lsum;
        float* op = out + (bq + qb + w * 16 + lr) * NH;
        #pragma unroll
        for (int hf = 0; hf < 4; ++hf) {
            f32x4 o = O[hf] * inv;
            *(f32x4*)&op[hf * 16 + lg * 4] = o;
        }
        return;
    }

    const int a8 = j >> 3, r8 = j & 7;
    const int pidx = b * 288 + (a8 + 1) * (4 * a8 + r8) + c;
    unsigned short* Po = pO + (size_t)pidx * 4096;
    #pragma unroll
    for (int hf = 0; hf < 4; ++hf) {
        bf16x4 pp;
        pp[0] = (short)f2bf(O[hf][0]); pp[1] = (short)f2bf(O[hf][1]);
        pp[2] = (short)f2bf(O[hf][2]); pp[3] = (short)f2bf(O[hf][3]);
        *(bf16x4*)&Po[(w * 16 + lr) * 64 + hf * 16 + lg * 4] = pp;
    }
    if (lane < 16) {
        pm[pidx * 64 + w * 16 + lane] = mrow;
        pl[pidx * 64 + w * 16 + lane] = lsum;
    }
    #undef STAGEKV
}

// ---------------------------------------------------------------------------
// Kernel 3: attention phase B — merge bf16 chunk partials, j >= 8 only.
// ---------------------------------------------------------------------------
__global__ __launch_bounds__(256) void attn_merge(
    const unsigned short* __restrict__ pO, const float* __restrict__ pm,
    const float* __restrict__ pl, float* __restrict__ out)
{
    const int bid = blockIdx.x;
    const int b = bid & 3, j = 8 + (bid >> 2);
    const int nch = (j >> 3) + 1;
    const int a8 = j >> 3, r8 = j & 7;
    const int pbase = b * 288 + (a8 + 1) * (4 * a8 + r8);
    const int tid = threadIdx.x;
    const int row = tid >> 2, hq = (tid & 3) * 16;

    float M = -3.0e38f, L = 0.f;
    f32x4 acc0 = {0,0,0,0}, acc1 = {0,0,0,0}, acc2 = {0,0,0,0}, acc3 = {0,0,0,0};
    for (int cc = 0; cc < nch; ++cc) {
        int pidx = pbase + cc;
        float mc = pm[pidx * 64 + row];
        float lc = pl[pidx * 64 + row];
        const unsigned short* po = pO + (size_t)pidx * 4096 + row * 64 + hq;
        bf16x8 r0 = *(const bf16x8*)po;
        bf16x8 r1 = *(const bf16x8*)(po + 8);
        float Mn = fmaxf(M, mc);
        float sO = __expf(M - Mn), sN = __expf(mc - Mn);
        L = L * sO + lc * sN;
        f32x4 v0 = {bf2f((unsigned short)r0[0]), bf2f((unsigned short)r0[1]),
                    bf2f((unsigned short)r0[2]), bf2f((unsigned short)r0[3])};
        f32x4 v1 = {bf2f((unsigned short)r0[4]), bf2f((unsigned short)r0[5]),
                    bf2f((unsigned short)r0[6]), bf2f((unsigned short)r0[7])};
        f32x4 v2 = {bf2f((unsigned short)r1[0]), bf2f((unsigned short)r1[1]),
                    bf2f((unsigned short)r1[2]), bf2f((unsigned short)r1[3])};
        f32x4 v3 = {bf2f((unsigned short)r1[4]), bf2f((unsigned short)r1[5]),
                    bf2f((unsigned short)r1[6]), bf2f((unsigned short)r1[7])};
        acc0 = acc0 * sO + v0 * sN;
        acc1 = acc1 * sO + v1 * sN;
        acc2 = acc2 * sO + v2 * sN;
        acc3 = acc3 * sO + v3 * sN;
        M = Mn;
    }
    float inv = 1.f / L;
    float* op = out + ((size_t)b * NS + (size_t)j * 64 + row) * NH + hq;
    *(f32x4*)(op + 0)  = acc0 * inv;
    *(f32x4*)(op + 4)  = acc1 * inv;
    *(f32x4*)(op + 8)  = acc2 * inv;
    *(f32x4*)(op + 12) = acc3 * inv;
}

extern "C" void kernel_launch(void* const* d_in, const int* in_sizes, int n_in,
                              void* d_out, int out_size, void* d_ws, size_t ws_size,
                              hipStream_t stream)
{
    const float* x  = (const float*)d_in[0];
    const float* Wq = (const float*)d_in[1];
    const float* Wk = (const float*)d_in[2];
    const float* Wv = (const float*)d_in[3];
    float* out = (float*)d_out;

    const size_t n = (size_t)NB * NS * NH;            // 1,048,576 elements
    unsigned short* qb_ = (unsigned short*)d_ws;      // 2 MB
    unsigned short* kb_ = qb_ + n;                    // 2 MB
    unsigned short* vT  = kb_ + n;                    // 2 MB (layout [b][h][s])
    unsigned short* wT  = vT + n;                     // 384 KB (layout [192][1024])
    unsigned short* pOb = wT + 192 * 1024;            // 1152 x 4096 bf16 = 9.4 MB
    float* pm_ = (float*)(pOb + (size_t)1152 * 4096); // 1152 x 64 f32
    float* pl_ = pm_ + 1152 * 64;                     // 1152 x 64 f32

    wconv<<<dim3(48), dim3(256), 0, stream>>>(Wq, Wk, Wv, wT);
    qkv_proj<<<dim3(512), dim3(512), 0, stream>>>(x, wT, qb_, kb_, vT);
    attn_part<<<dim3(2048), dim3(256), 0, stream>>>(qb_, kb_, vT, pOb, pm_, pl_, out);
    attn_merge<<<dim3(224), dim3(256), 0, stream>>>(pOb, pm_, pl_, out);
}